// Round 1
// baseline (484.913 us; speedup 1.0000x reference)
//
#include <hip/hip_runtime.h>

// Multi-step integrate-and-fire (T=16 scan over independent elements).
// x_seq: (16, 32, 128, 32, 32) fp32 -> spikes same shape.
// Memory-bound: 512 MiB total traffic, floor ~85us at 6.3 TB/s.

#define T_STEPS 16

__global__ __launch_bounds__(256) void if_scan_kernel(
    const float4* __restrict__ x, float4* __restrict__ out, int n4) {
    int i = blockIdx.x * blockDim.x + threadIdx.x;
    if (i >= n4) return;

    float4 v = make_float4(0.f, 0.f, 0.f, 0.f);

#pragma unroll
    for (int t = 0; t < T_STEPS; ++t) {
        size_t idx = (size_t)t * (size_t)n4 + (size_t)i;
        float4 xt = x[idx];
        v.x += xt.x; v.y += xt.y; v.z += xt.z; v.w += xt.w;
        float4 s;
        s.x = (v.x >= 1.0f) ? 1.0f : 0.0f;
        s.y = (v.y >= 1.0f) ? 1.0f : 0.0f;
        s.z = (v.z >= 1.0f) ? 1.0f : 0.0f;
        s.w = (v.w >= 1.0f) ? 1.0f : 0.0f;
        v.x -= s.x; v.y -= s.y; v.z -= s.z; v.w -= s.w;
        out[idx] = s;
    }
}

extern "C" void kernel_launch(void* const* d_in, const int* in_sizes, int n_in,
                              void* d_out, int out_size, void* d_ws, size_t ws_size,
                              hipStream_t stream) {
    const float* x = (const float*)d_in[0];
    float* out = (float*)d_out;

    // total elements = T * per_step; per_step in float4 units
    int total = in_sizes[0];             // 16*32*128*32*32 = 67108864
    int per_step = total / T_STEPS;      // 4194304
    int n4 = per_step / 4;               // 1048576 float4 per timestep

    dim3 block(256);
    dim3 grid((n4 + block.x - 1) / block.x);
    if_scan_kernel<<<grid, block, 0, stream>>>(
        (const float4*)x, (float4*)out, n4);
}

// Round 3
// 458.797 us; speedup vs baseline: 1.0569x; 1.0569x over previous
//
#include <hip/hip_runtime.h>

// Multi-step integrate-and-fire (T=16 scan over independent elements).
// x_seq: (16, 32, 128, 32, 32) fp32 -> spikes same shape.
// Memory-bound streaming: 256 MiB in + 256 MiB out.
// R1: rocprof showed WRITE_SIZE 330MB (>268MB ideal) + only 1.86 TB/s write BW
//     -> L3 thrash between input (restored hot by harness) and output stream.
// Fix: non-temporal stores for output (no write-allocate, keep input in L3),
//      2x float4 per thread for MLP.
// R2: __builtin_nontemporal_store needs a clang ext_vector type, not HIP's
//     float4 struct -> use f32x4 typedef.

#define T_STEPS 16

typedef float f32x4 __attribute__((ext_vector_type(4)));

__global__ __launch_bounds__(256) void if_scan_kernel(
    const f32x4* __restrict__ x, f32x4* __restrict__ out, int n4) {
    int i = (blockIdx.x * blockDim.x + threadIdx.x) * 2;
    if (i >= n4) return;

    f32x4 v0 = (f32x4)(0.f);
    f32x4 v1 = (f32x4)(0.f);

#pragma unroll
    for (int t = 0; t < T_STEPS; ++t) {
        size_t idx = (size_t)t * (size_t)n4 + (size_t)i;
        f32x4 a = x[idx];
        f32x4 b = x[idx + 1];

        v0 += a;
        v1 += b;

        f32x4 s0, s1;
        s0.x = (v0.x >= 1.0f) ? 1.0f : 0.0f;
        s0.y = (v0.y >= 1.0f) ? 1.0f : 0.0f;
        s0.z = (v0.z >= 1.0f) ? 1.0f : 0.0f;
        s0.w = (v0.w >= 1.0f) ? 1.0f : 0.0f;
        s1.x = (v1.x >= 1.0f) ? 1.0f : 0.0f;
        s1.y = (v1.y >= 1.0f) ? 1.0f : 0.0f;
        s1.z = (v1.z >= 1.0f) ? 1.0f : 0.0f;
        s1.w = (v1.w >= 1.0f) ? 1.0f : 0.0f;

        v0 -= s0;
        v1 -= s1;

        __builtin_nontemporal_store(s0, &out[idx]);
        __builtin_nontemporal_store(s1, &out[idx + 1]);
    }
}

extern "C" void kernel_launch(void* const* d_in, const int* in_sizes, int n_in,
                              void* d_out, int out_size, void* d_ws, size_t ws_size,
                              hipStream_t stream) {
    const float* x = (const float*)d_in[0];
    float* out = (float*)d_out;

    int total = in_sizes[0];             // 16*32*128*32*32 = 67108864
    int per_step = total / T_STEPS;      // 4194304
    int n4 = per_step / 4;               // 1048576 float4 per timestep

    int threads_needed = (n4 + 1) / 2;   // 2 float4 per thread
    dim3 block(256);
    dim3 grid((threads_needed + block.x - 1) / block.x);
    if_scan_kernel<<<grid, block, 0, stream>>>(
        (const f32x4*)x, (f32x4*)out, n4);
}